// Round 9
// baseline (448.468 us; speedup 1.0000x reference)
//
#include <hip/hip_runtime.h>
#include <hip/hip_bf16.h>
#include <math.h>

#define B 4
#define NF 64
#define H 128
#define W 128
#define HW (H*W)
#define TOPK 3
#define NRB 8

typedef __attribute__((ext_vector_type(8))) short short8;
typedef __attribute__((ext_vector_type(4))) float f32x4;
typedef __attribute__((ext_vector_type(4))) int i32x4;
typedef __attribute__((ext_vector_type(4))) unsigned short u16x4;

static __device__ __forceinline__ float b2f(short s) {
    union { unsigned u; float f; } cv;
    cv.u = ((unsigned)(unsigned short)s) << 16;
    return cv.f;
}
static __device__ __forceinline__ short f2bf(float f) {
    union { float f; unsigned u; } cv; cv.f = f;
    unsigned r = (cv.u + 0x7FFFu + ((cv.u >> 16) & 1u)) >> 16;
    return (short)r;
}

__device__ __forceinline__ float cubicw(float d) {
    float at = fabsf(d);
    if (at <= 1.0f) return (1.25f * at - 2.25f) * at * at + 1.0f;
    if (at < 2.0f)  return -0.75f * (((at - 5.0f) * at + 8.0f) * at - 4.0f);
    return 0.0f;
}

// -------- pack x + 3x (T_i * Sup_i) into channel-last bf16 (bicubic inline) --------
__global__ __launch_bounds__(256) void pack_all(
    const float* __restrict__ x, const float* __restrict__ T,
    const float* __restrict__ S,
    __hip_bfloat16* __restrict__ xcl, __hip_bfloat16* __restrict__ refcl)
{
    int tb = blockIdx.x >> 10;            // 0: x, 1..3: T_i
    int bx = blockIdx.x & 1023;
    int b = bx >> 8;
    int p0 = (bx & 255) * 64;
    int tid = threadIdx.x;
    const float* src; short* dst;
    float supv = 1.0f;
    int p = tid & 63, c4 = tid >> 6;
    if (tb == 0) { src = x; dst = (short*)xcl; }
    else {
        int i = tb - 1;
        src = T + (size_t)i * B * 64 * HW;
        dst = (short*)refcl + (size_t)i * B * HW * 64;
        int gp = p0 + p;
        int gy = gp >> 7, gx = gp & 127;
        const float* Sp = S + (size_t)(i * B + b) * 64 * 64;
        float srcy = (gy + 0.5f) * 0.5f - 0.5f;
        float srcx = (gx + 0.5f) * 0.5f - 0.5f;
        float y0f = floorf(srcy), x0f = floorf(srcx);
        float ty = srcy - y0f, tx = srcx - x0f;
        int iy0 = (int)y0f, ix0 = (int)x0f;
        float acc = 0.f;
#pragma unroll
        for (int j = 0; j < 4; j++) {
            int yy = min(max(iy0 + j - 1, 0), 63);
            float wy = cubicw(ty - (float)(j - 1));
            float r = 0.f;
#pragma unroll
            for (int k = 0; k < 4; k++) {
                int xx = min(max(ix0 + k - 1, 0), 63);
                r += cubicw(tx - (float)(k - 1)) * Sp[yy * 64 + xx];
            }
            acc += wy * r;
        }
        supv = acc;
    }
    __shared__ short ls[64 * 72];
#pragma unroll
    for (int cc = 0; cc < 16; cc++) {
        int c = cc * 4 + c4;
        float v = src[((size_t)b * 64 + c) * HW + p0 + p] * supv;
        ls[p * 72 + c] = f2bf(v);
    }
    __syncthreads();
    for (int it = tid; it < 512; it += 256) {
        int pp = it >> 3, oct = it & 7;
        short8 v = *(short8*)&ls[pp * 72 + oct * 8];
        *(short8*)&dst[((size_t)b * HW + p0 + pp) * 64 + oct * 8] = v;
    }
}

__global__ __launch_bounds__(256) void unpack_cl(
    const __hip_bfloat16* __restrict__ src, float* __restrict__ dst)
{
    int bx = blockIdx.x;
    int b = bx >> 8;
    int p0 = (bx & 255) * 64;
    int tid = threadIdx.x;
    __shared__ short ls[64 * 72];
    const short* s = (const short*)src;
    for (int it = tid; it < 512; it += 256) {
        int pp = it >> 3, oct = it & 7;
        short8 v = *(const short8*)&s[((size_t)b * HW + p0 + pp) * 64 + oct * 8];
        *(short8*)&ls[pp * 72 + oct * 8] = v;
    }
    __syncthreads();
    int p = tid & 63, c4 = tid >> 6;
#pragma unroll
    for (int cc = 0; cc < 16; cc++) {
        int c = cc * 4 + c4;
        dst[((size_t)b * 64 + c) * HW + p0 + p] = b2f(ls[p * 72 + c]);
    }
}

// -------- weight prep: B-fragments (bf16, per-lane order) --------
#define RB_ITEMS   (16*18*4*64)   // 73728
#define FUSE_ITEMS (36*4*64)      // 9216
#define OM_ITEMS   (3*36*2*64)    // 13824
#define DF_ITEMS   (3*18*4*64)    // 13824
#define FUSE_OFF   RB_ITEMS
#define OM_OFF     (RB_ITEMS + FUSE_ITEMS)
#define DF_OFF     (OM_OFF + OM_ITEMS)
#define PREP_TOTAL (RB_ITEMS + FUSE_ITEMS + OM_ITEMS + DF_ITEMS)

__global__ __launch_bounds__(256) void prep_weights(
    const float* __restrict__ rb_w1, const float* __restrict__ rb_w2,
    const float* __restrict__ fuse_w,
    const float* __restrict__ off_w, const float* __restrict__ mod_w,
    const float* __restrict__ reg_w,
    short* __restrict__ bfrag)
{
    int idx = blockIdx.x * 256 + threadIdx.x;
    if (idx >= PREP_TOTAL) return;
    short o8[8];
    if (idx < OM_OFF) {
        int lane, s, nt, n, Cin;
        const float* src;
        if (idx < RB_ITEMS) {
            int conv = idx / 4608, rem = idx % 4608;
            s = rem >> 8; nt = (rem >> 6) & 3; lane = rem & 63;
            n = nt * 16 + (lane & 15); Cin = 64;
            src = ((conv & 1) ? rb_w2 : rb_w1) + (size_t)(conv >> 1) * 64 * 64 * 9;
        } else {
            int rem = idx - FUSE_OFF;
            s = rem >> 8; nt = (rem >> 6) & 3; lane = rem & 63;
            n = nt * 16 + (lane & 15); Cin = 128;
            src = fuse_w;
        }
        int ph = (s >= 18); int sl = s - ph * 18;
        int tap = sl >> 1, ih = sl & 1;
        int quad = lane >> 4;
#pragma unroll
        for (int j = 0; j < 8; j++) {
            int ic = ph * 64 + ih * 32 + quad * 8 + j;
            o8[j] = f2bf(src[((size_t)n * Cin + ic) * 9 + tap]);
        }
    } else if (idx < DF_OFF) {
        int rem = idx - OM_OFF;
        int i = rem / 4608; int rem2 = rem % 4608;
        int s = rem2 >> 7; int nt = (rem2 >> 6) & 1; int lane = rem2 & 63;
        int n = nt * 16 + (lane & 15);
        int ph = (s >= 18); int sl = s - ph * 18;
        int tap = sl >> 1, ih = sl & 1;
        int quad = lane >> 4;
#pragma unroll
        for (int j = 0; j < 8; j++) {
            int ic = ph * 64 + ih * 32 + quad * 8 + j;
            float v = 0.f;
            if (n < 18)      v = off_w[(((size_t)i * 18 + n) * 128 + ic) * 9 + tap];
            else if (n < 27) v = mod_w[(((size_t)i * 9 + n - 18) * 128 + ic) * 9 + tap];
            o8[j] = f2bf(v);
        }
    } else {
        int e = idx - DF_OFF;
        int i = e / 4608; int rem = e % 4608;
        int s = rem >> 8; int nt = (rem >> 6) & 3; int lane = rem & 63;
        int tap = s >> 1;
        int n = nt * 16 + (lane & 15);
        int cb = (s & 1) * 32 + (lane >> 4) * 8;
#pragma unroll
        for (int j = 0; j < 8; j++)
            o8[j] = f2bf(reg_w[(((size_t)i * 64 + n) * 64 + cb + j) * 9 + tap]);
    }
    *(short8*)&bfrag[(size_t)idx * 8] = *(short8*)o8;
}

// -------- implicit-GEMM 3x3 conv via MFMA, 8x8 pixel tile, 4 blocks/CU --------
// EPI 2: +resid (CL bf16 out);  EPI 3: offmod (i = blockIdx.x>>10, bf16 [pix][32] out)
template<int NPH, int NT, int EPI>
__global__ __launch_bounds__(256, 4) void conv_mfma8(
    const __hip_bfloat16* __restrict__ in0,
    const __hip_bfloat16* __restrict__ in1,
    const short* __restrict__ bfrag,
    const float* __restrict__ bias0,
    const float* __restrict__ bias1,
    const __hip_bfloat16* __restrict__ resid,
    __hip_bfloat16* __restrict__ outcl)
{
    int bx = blockIdx.x;
    int i = 0;
    if (EPI == 3) { i = bx >> 10; bx &= 1023; }
    int b = bx >> 8, tile = bx & 255;
    int ty0 = (tile >> 4) << 3, tx0 = (tile & 15) << 3;
    int tid = threadIdx.x;
    int wid = tid >> 6, lane = tid & 63, quad = lane >> 4, lrow = lane & 15;
    __shared__ short smem[100 * 72];
    f32x4 acc[NT];
#pragma unroll
    for (int nt = 0; nt < NT; nt++) acc[nt] = f32x4{0.f, 0.f, 0.f, 0.f};

    const short* in1b = (const short*)in1 + (size_t)i * B * HW * 64;
    const short* bfb  = bfrag + (size_t)i * 4608 * 8;

    for (int ph = 0; ph < NPH; ph++) {
        const short* src = (ph ? in1b : (const short*)in0) + (size_t)b * HW * 64;
        __syncthreads();
        for (int it = tid; it < 800; it += 256) {
            int p = it >> 3, oct = it & 7;
            int r = (p * 205) >> 11, c = p - r * 10;
            int gy = ty0 + r - 1, gx = tx0 + c - 1;
            short8 v{};
            if (gy >= 0 && gy < H && gx >= 0 && gx < W)
                v = *(const short8*)&src[((size_t)(gy * W + gx)) * 64 + oct * 8];
            *(short8*)&smem[p * 72 + oct * 8] = v;
        }
        __syncthreads();
        const short* bptr = bfb + (size_t)(ph * 18) * NT * 64 * 8;
        short8 bcur[NT];
#pragma unroll
        for (int nt = 0; nt < NT; nt++)
            bcur[nt] = *(const short8*)&bptr[(size_t)(nt * 64 + lane) * 8];
        int pm = wid * 16 + lrow;
        int rr0 = pm >> 3, cc0 = pm & 7;
        for (int s = 0; s < 18; s++) {
            int tap = s >> 1, ih = s & 1;
            int dy = tap / 3, dx = tap - dy * 3;
            short8 afr = *(const short8*)
                &smem[((rr0 + dy) * 10 + cc0 + dx) * 72 + ih * 32 + quad * 8];
            short8 bnxt[NT] = {};
            if (s < 17) {
#pragma unroll
                for (int nt = 0; nt < NT; nt++)
                    bnxt[nt] = *(const short8*)&bptr[(size_t)(((s + 1) * NT + nt) * 64 + lane) * 8];
            }
#pragma unroll
            for (int nt = 0; nt < NT; nt++)
                acc[nt] = __builtin_amdgcn_mfma_f32_16x16x32_bf16(
                    afr, bcur[nt], acc[nt], 0, 0, 0);
#pragma unroll
            for (int nt = 0; nt < NT; nt++) bcur[nt] = bnxt[nt];
        }
    }
    const float* b0 = bias0 + (EPI == 3 ? i * 18 : 0);
    const float* b1 = (EPI == 3) ? bias1 + i * 9 : nullptr;
    short* outp = (short*)outcl + (EPI == 3 ? (size_t)i * B * HW * 32 : (size_t)0);
#pragma unroll
    for (int nt = 0; nt < NT; nt++) {
        int n = nt * 16 + lrow;
#pragma unroll
        for (int r = 0; r < 4; r++) {
            int p = wid * 16 + quad * 4 + r;
            int gy = ty0 + (p >> 3), gx = tx0 + (p & 7);
            size_t pix = (size_t)b * HW + gy * W + gx;
            float v = acc[nt][r];
            if (EPI == 3) {
                if (n < 18) { v += b0[n]; v = fminf(fmaxf(v, -32.f), 32.f); }
                else if (n < 27) { v += b1[n - 18]; v = 2.f / (1.f + expf(-v)); }
                else v = 0.f;
                outp[pix * 32 + n] = f2bf(v);
            } else {
                v += b0[n];
                v += b2f(((const short*)resid)[pix * 64 + n]);
                outp[pix * 64 + n] = f2bf(v);
            }
        }
    }
}

// -------- fused residual block, 16x8 tile, B-frags reused + pipelined --------
// out = in + conv2(relu(conv1(in))); conv1 halo outputs outside image forced to 0.
__global__ __launch_bounds__(256, 2) void rb_fused(
    const __hip_bfloat16* __restrict__ incl,
    const short* __restrict__ bf1, const short* __restrict__ bf2,
    const float* __restrict__ bias1, const float* __restrict__ bias2,
    __hip_bfloat16* __restrict__ outcl)
{
    int bx = blockIdx.x;                  // 512 blocks: b(4) x rt(8) x ct(16)
    int b = bx >> 7, tile = bx & 127;
    int ty0 = (tile >> 4) << 4, tx0 = (tile & 15) << 3;
    int tid = threadIdx.x;
    int wid = tid >> 6, lane = tid & 63, quad = lane >> 4, lrow = lane & 15;
    __shared__ short s1[240 * 72];   // input 20x12 halo (2-ring)
    __shared__ short s2[180 * 72];   // conv1 output 18x10 (1-ring)

    const short* src = (const short*)incl + (size_t)b * HW * 64;
    for (int it = tid; it < 1920; it += 256) {
        int p = it >> 3, oct = it & 7;
        int r = (p * 342) >> 12, c = p - r * 12;
        int gy = ty0 + r - 2, gx = tx0 + c - 2;
        short8 v{};
        if (gy >= 0 && gy < H && gx >= 0 && gx < W)
            v = *(const short8*)&src[((size_t)(gy * W + gx)) * 64 + oct * 8];
        *(short8*)&s1[p * 72 + oct * 8] = v;
    }
    __syncthreads();

    // conv1: 180 px (18x10), 12 M-tiles; wave handles tiles {wid, wid+4, wid+8}
    {
        int ra[3], ca[3];
#pragma unroll
        for (int t = 0; t < 3; t++) {
            int pa = min((wid + t * 4) * 16 + lrow, 179);
            ra[t] = (pa * 205) >> 11; ca[t] = pa - ra[t] * 10;
        }
        f32x4 a1[3][4];
#pragma unroll
        for (int t = 0; t < 3; t++)
#pragma unroll
            for (int nt = 0; nt < 4; nt++) a1[t][nt] = f32x4{0.f, 0.f, 0.f, 0.f};
        short8 bcur[4];
#pragma unroll
        for (int nt = 0; nt < 4; nt++)
            bcur[nt] = *(const short8*)&bf1[(size_t)(nt * 64 + lane) * 8];
        for (int s = 0; s < 18; s++) {
            int tap = s >> 1, ih = s & 1;
            int dy = tap / 3, dx = tap - dy * 3;
            int choff = ih * 32 + quad * 8;
            short8 bnxt[4] = {};
            if (s < 17) {
#pragma unroll
                for (int nt = 0; nt < 4; nt++)
                    bnxt[nt] = *(const short8*)&bf1[(size_t)(((s + 1) * 4 + nt) * 64 + lane) * 8];
            }
#pragma unroll
            for (int t = 0; t < 3; t++) {
                short8 afr = *(const short8*)
                    &s1[((ra[t] + dy) * 12 + ca[t] + dx) * 72 + choff];
#pragma unroll
                for (int nt = 0; nt < 4; nt++)
                    a1[t][nt] = __builtin_amdgcn_mfma_f32_16x16x32_bf16(
                        afr, bcur[nt], a1[t][nt], 0, 0, 0);
            }
#pragma unroll
            for (int nt = 0; nt < 4; nt++) bcur[nt] = bnxt[nt];
        }
#pragma unroll
        for (int t = 0; t < 3; t++)
#pragma unroll
            for (int nt = 0; nt < 4; nt++) {
                int n = nt * 16 + lrow;
#pragma unroll
                for (int r = 0; r < 4; r++) {
                    int p = (wid + t * 4) * 16 + quad * 4 + r;
                    if (p < 180) {
                        int rw = (p * 205) >> 11, cw = p - rw * 10;
                        int gy1 = ty0 - 1 + rw, gx1 = tx0 - 1 + cw;
                        float v = fmaxf(a1[t][nt][r] + bias1[n], 0.f);
                        if (gy1 < 0 || gy1 >= H || gx1 < 0 || gx1 >= W) v = 0.f;
                        s2[p * 72 + n] = f2bf(v);
                    }
                }
            }
    }
    __syncthreads();

    // conv2: 128 px (16x8), 8 M-tiles; wave handles tiles {wid, wid+4}
    {
        int rr[2], cc[2];
#pragma unroll
        for (int t = 0; t < 2; t++) {
            int pa = (wid + t * 4) * 16 + lrow;
            rr[t] = pa >> 3; cc[t] = pa & 7;
        }
        f32x4 a2[2][4];
#pragma unroll
        for (int t = 0; t < 2; t++)
#pragma unroll
            for (int nt = 0; nt < 4; nt++) a2[t][nt] = f32x4{0.f, 0.f, 0.f, 0.f};
        short8 bcur[4];
#pragma unroll
        for (int nt = 0; nt < 4; nt++)
            bcur[nt] = *(const short8*)&bf2[(size_t)(nt * 64 + lane) * 8];
        for (int s = 0; s < 18; s++) {
            int tap = s >> 1, ih = s & 1;
            int dy = tap / 3, dx = tap - dy * 3;
            int choff = ih * 32 + quad * 8;
            short8 bnxt[4] = {};
            if (s < 17) {
#pragma unroll
                for (int nt = 0; nt < 4; nt++)
                    bnxt[nt] = *(const short8*)&bf2[(size_t)(((s + 1) * 4 + nt) * 64 + lane) * 8];
            }
#pragma unroll
            for (int t = 0; t < 2; t++) {
                short8 afr = *(const short8*)
                    &s2[((rr[t] + dy) * 10 + cc[t] + dx) * 72 + choff];
#pragma unroll
                for (int nt = 0; nt < 4; nt++)
                    a2[t][nt] = __builtin_amdgcn_mfma_f32_16x16x32_bf16(
                        afr, bcur[nt], a2[t][nt], 0, 0, 0);
            }
#pragma unroll
            for (int nt = 0; nt < 4; nt++) bcur[nt] = bnxt[nt];
        }
#pragma unroll
        for (int t = 0; t < 2; t++)
#pragma unroll
            for (int nt = 0; nt < 4; nt++) {
                int n = nt * 16 + lrow;
#pragma unroll
                for (int r = 0; r < 4; r++) {
                    int p = (wid + t * 4) * 16 + quad * 4 + r;
                    int pr = p >> 3, pc = p & 7;
                    float res = b2f(s1[((pr + 2) * 12 + pc + 2) * 72 + n]);
                    float v = a2[t][nt][r] + bias2[n] + res;
                    ((short*)outcl)[((size_t)b * HW + (ty0 + pr) * W + tx0 + pc) * 64 + n] = f2bf(v);
                }
            }
    }
}

// -------- deformable conv: LDS-window gathers, fully software-pipelined --------
__global__ __launch_bounds__(256, 3) void deform_all(
    const __hip_bfloat16* __restrict__ refcl, // [3][B][HW][64]
    const __hip_bfloat16* __restrict__ ombf,  // [3][B][HW][32]
    const short* __restrict__ dfrag,          // [3][18][4][64][8]
    const float* __restrict__ regb,           // [3][64]
    __hip_bfloat16* __restrict__ attbf)       // [B][HW][64]
{
    int bx = blockIdx.x;
    int b = bx >> 8, tile = bx & 255;
    int ty0 = (tile >> 4) << 3, tx0 = (tile & 15) << 3;
    int wy0 = ty0 - 3, wx0 = tx0 - 3;
    int tid = threadIdx.x;
    int wid = tid >> 6, lane = tid & 63, quad = lane >> 4, lrow = lane & 15;

    __shared__ short win[196 * 72];            // 14x14 px window, 28.2 KB
    __shared__ i32x4 taddr[9][64];
    __shared__ f32x4 twt[9][64];
    __shared__ unsigned short lad[9][64][4];
    __shared__ unsigned short sflag[9][64];

    f32x4 acc[4];
#pragma unroll
    for (int nt = 0; nt < 4; nt++) acc[nt] = f32x4{0.f, 0.f, 0.f, 0.f};
    int pl = wid * 16 + lrow;
    int qoff = quad * 8;

    for (int i = 0; i < TOPK; i++) {
        const short* rb_ = (const short*)refcl + (size_t)(i * B + b) * HW * 64;
        const short* omp_base = (const short*)ombf + (size_t)(i * B + b) * HW * 32;
        __syncthreads();
        // stage 14x14 window (zero-filled outside image)
        for (int it = tid; it < 1568; it += 256) {
            int p = it >> 3, oct = it & 7;
            int r = (p * 293) >> 12, c = p - r * 14;
            int gy = wy0 + r, gx = wx0 + c;
            short8 v{};
            if (gy >= 0 && gy < H && gx >= 0 && gx < W)
                v = *(const short8*)&rb_[((size_t)(gy * W + gx)) * 64 + oct * 8];
            *(short8*)&win[p * 72 + oct * 8] = v;
        }
        // tap tables
        for (int e = tid; e < 576; e += 256) {
            int k = e >> 6, p = e & 63;
            int py_ = ty0 + (p >> 3), px_ = tx0 + (p & 7);
            const short* omp = omp_base + (size_t)(py_ * W + px_) * 32;
            int ky = k / 3, kx = k - ky * 3;
            float oy = b2f(omp[2 * k]), ox = b2f(omp[2 * k + 1]), mk = b2f(omp[18 + k]);
            float py = (float)(py_ - 1 + ky) + oy;
            float px = (float)(px_ - 1 + kx) + ox;
            float y0f = floorf(py), x0f = floorf(px);
            float fy = py - y0f, fx = px - x0f;
            int y0 = (int)y0f, x0 = (int)x0f;
            int y1 = y0 + 1, x1 = x0 + 1;
            float vy0 = (y0 >= 0 && y0 < H) ? 1.f : 0.f;
            float vy1 = (y1 >= 0 && y1 < H) ? 1.f : 0.f;
            float vx0 = (x0 >= 0 && x0 < W) ? 1.f : 0.f;
            float vx1 = (x1 >= 0 && x1 < W) ? 1.f : 0.f;
            int y0c = min(max(y0, 0), H - 1), y1c = min(max(y1, 0), H - 1);
            int x0c = min(max(x0, 0), W - 1), x1c = min(max(x1, 0), W - 1);
            taddr[k][p] = i32x4{(y0c * W + x0c) * 64, (y0c * W + x1c) * 64,
                                (y1c * W + x0c) * 64, (y1c * W + x1c) * 64};
            twt[k][p] = f32x4{(1.f - fy) * (1.f - fx) * vy0 * vx0 * mk,
                              (1.f - fy) * fx * vy0 * vx1 * mk,
                              fy * (1.f - fx) * vy1 * vx0 * mk,
                              fy * fx * vy1 * vx1 * mk};
            int fast = (y0c >= wy0) && (y1c <= wy0 + 13) &&
                       (x0c >= wx0) && (x1c <= wx0 + 13);
            sflag[k][p] = fast ? 0 : 1;
            if (fast) {
                lad[k][p][0] = (unsigned short)(((y0c - wy0) * 14 + (x0c - wx0)) * 72);
                lad[k][p][1] = (unsigned short)(((y0c - wy0) * 14 + (x1c - wx0)) * 72);
                lad[k][p][2] = (unsigned short)(((y1c - wy0) * 14 + (x0c - wx0)) * 72);
                lad[k][p][3] = (unsigned short)(((y1c - wy0) * 14 + (x1c - wx0)) * 72);
            } else {
                lad[k][p][0] = 0; lad[k][p][1] = 0; lad[k][p][2] = 0; lad[k][p][3] = 0;
            }
        }
        __syncthreads();

        const short* dfr = dfrag + (size_t)i * 18 * 4 * 64 * 8;

        // pipeline prologue: s=0 bundle
        u16x4 lp = *(const u16x4*)&lad[0][pl][0];
        f32x4 tw = twt[0][pl];
        int slowc = sflag[0][pl];
        short8 c00 = *(const short8*)&win[lp.x + qoff];
        short8 c01 = *(const short8*)&win[lp.y + qoff];
        short8 c10 = *(const short8*)&win[lp.z + qoff];
        short8 c11 = *(const short8*)&win[lp.w + qoff];
        short8 bcur[4];
#pragma unroll
        for (int nt = 0; nt < 4; nt++)
            bcur[nt] = *(const short8*)&dfr[(size_t)(nt * 64 + lane) * 8];

        for (int s = 0; s < 18; s++) {
            int tap = s >> 1, ih = s & 1;
            int choff = ih * 32 + qoff;
            // prefetch s+1 bundle (clamped at tail; redundant loads are harmless)
            int sn = (s < 17) ? s + 1 : 17;
            int tapn = sn >> 1, ihn = sn & 1;
            int choffn = ihn * 32 + qoff;
            u16x4 lpn = *(const u16x4*)&lad[tapn][pl][0];
            f32x4 twn = twt[tapn][pl];
            int slown = sflag[tapn][pl];
            short8 n00 = *(const short8*)&win[lpn.x + choffn];
            short8 n01 = *(const short8*)&win[lpn.y + choffn];
            short8 n10 = *(const short8*)&win[lpn.z + choffn];
            short8 n11 = *(const short8*)&win[lpn.w + choffn];
            short8 bnxt[4];
#pragma unroll
            for (int nt = 0; nt < 4; nt++)
                bnxt[nt] = *(const short8*)&dfr[(size_t)((sn * 4 + nt) * 64 + lane) * 8];
            // rare slow path for current step
            if (__ballot(slowc)) {
                i32x4 ta = taddr[tap][pl];
                const short* base = rb_ + choff;
                short8 g00 = *(const short8*)&base[ta.x];
                short8 g01 = *(const short8*)&base[ta.y];
                short8 g10 = *(const short8*)&base[ta.z];
                short8 g11 = *(const short8*)&base[ta.w];
                if (slowc) { c00 = g00; c01 = g01; c10 = g10; c11 = g11; }
            }
            // blend + MFMA
            short af[8];
#pragma unroll
            for (int j = 0; j < 8; j++) {
                float sk = b2f(c00[j]) * tw.x + b2f(c01[j]) * tw.y
                         + b2f(c10[j]) * tw.z + b2f(c11[j]) * tw.w;
                af[j] = f2bf(sk);
            }
            short8 afr = *(short8*)af;
#pragma unroll
            for (int nt = 0; nt < 4; nt++)
                acc[nt] = __builtin_amdgcn_mfma_f32_16x16x32_bf16(
                    afr, bcur[nt], acc[nt], 0, 0, 0);
            // shift pipeline
            c00 = n00; c01 = n01; c10 = n10; c11 = n11;
            tw = twn; slowc = slown;
#pragma unroll
            for (int nt = 0; nt < 4; nt++) bcur[nt] = bnxt[nt];
        }
    }
#pragma unroll
    for (int nt = 0; nt < 4; nt++) {
        int n = nt * 16 + lrow;
        float rbs = regb[n] + regb[64 + n] + regb[128 + n];
#pragma unroll
        for (int r = 0; r < 4; r++) {
            int p = wid * 16 + quad * 4 + r;
            int gy = ty0 + (p >> 3), gx = tx0 + (p & 7);
            ((short*)attbf)[((size_t)b * HW + gy * W + gx) * 64 + n] =
                f2bf(acc[nt][r] + rbs);
        }
    }
}

extern "C" void kernel_launch(void* const* d_in, const int* in_sizes, int n_in,
                              void* d_out, int out_size, void* d_ws, size_t ws_size,
                              hipStream_t stream) {
    const float* x      = (const float*)d_in[0];
    const float* T      = (const float*)d_in[1];
    const float* S      = (const float*)d_in[2];
    const float* off_w  = (const float*)d_in[3];
    const float* off_b  = (const float*)d_in[4];
    const float* mod_w  = (const float*)d_in[5];
    const float* mod_b  = (const float*)d_in[6];
    const float* reg_w  = (const float*)d_in[7];
    const float* reg_b  = (const float*)d_in[8];
    const float* fuse_w = (const float*)d_in[9];
    const float* fuse_b = (const float*)d_in[10];
    const float* rb_w1  = (const float*)d_in[11];
    const float* rb_b1  = (const float*)d_in[12];
    const float* rb_w2  = (const float*)d_in[13];
    const float* rb_b2  = (const float*)d_in[14];

    __hip_bfloat16* ombf  = (__hip_bfloat16*)d_ws;   // 3*B*HW*32
    __hip_bfloat16* refcl = ombf + 6291456;          // 3*B*HW*64
    __hip_bfloat16* xcl   = refcl + 12582912;
    __hip_bfloat16* xclb  = xcl + 4194304;
    __hip_bfloat16* xclb2 = xclb + 4194304;
    __hip_bfloat16* attbf = xclb2 + 4194304;
    short* bfrag = (short*)(attbf + 4194304);        // PREP_TOTAL*8 shorts

    prep_weights<<<(PREP_TOTAL + 255) / 256, 256, 0, stream>>>(
        rb_w1, rb_w2, fuse_w, off_w, mod_w, reg_w, bfrag);
    pack_all<<<4096, 256, 0, stream>>>(x, T, S, xcl, refcl);

    conv_mfma8<2, 2, 3><<<3072, 256, 0, stream>>>(
        xcl, refcl, bfrag + (size_t)OM_OFF * 8,
        off_b, mod_b, nullptr, ombf);

    deform_all<<<1024, 256, 0, stream>>>(
        refcl, ombf, bfrag + (size_t)DF_OFF * 8, reg_b, attbf);

    conv_mfma8<2, 4, 2><<<1024, 256, 0, stream>>>(
        xcl, attbf, bfrag + (size_t)FUSE_OFF * 8,
        fuse_b, nullptr, xcl, xclb);

    __hip_bfloat16* cur = xclb;
    __hip_bfloat16* alt = xclb2;
    for (int r = 0; r < NRB; r++) {
        rb_fused<<<512, 256, 0, stream>>>(
            cur, bfrag + (size_t)(r * 2) * 4608 * 8,
            bfrag + (size_t)(r * 2 + 1) * 4608 * 8,
            rb_b1 + r * 64, rb_b2 + r * 64, alt);
        __hip_bfloat16* t2 = cur; cur = alt; alt = t2;
    }
    unpack_cl<<<1024, 256, 0, stream>>>(cur, (float*)d_out);
}